// Round 3
// baseline (236.351 us; speedup 1.0000x reference)
//
#include <hip/hip_runtime.h>
#include <hip/hip_bf16.h>
#include <stdint.h>

// ---------- types ----------
typedef __bf16 bf16_t;
typedef bf16_t bf16x4 __attribute__((ext_vector_type(4)));
typedef bf16_t bf16x8 __attribute__((ext_vector_type(8)));
typedef float  f32x4  __attribute__((ext_vector_type(4)));
typedef float  f32x16 __attribute__((ext_vector_type(16)));

#define MFMA16(a, b, c) __builtin_amdgcn_mfma_f32_16x16x32_bf16((a), (b), (c), 0, 0, 0)
#define MFMA32(a, b, c) __builtin_amdgcn_mfma_f32_32x32x16_bf16((a), (b), (c), 0, 0, 0)

static __device__ __forceinline__ unsigned short f2bf(float f) {
    __hip_bfloat16 h = __float2bfloat16(f);
    return __builtin_bit_cast(unsigned short, h);
}
static __device__ __forceinline__ unsigned int pk2(float a, float b) {
    return ((unsigned int)f2bf(b) << 16) | (unsigned int)f2bf(a);
}

static __device__ __forceinline__ void gld_lds16(const void* g, void* l) {
    __builtin_amdgcn_global_load_lds(
        (const __attribute__((address_space(1))) uint32_t*)g,
        (__attribute__((address_space(3))) uint32_t*)l, 16, 0, 0);
}

// ---------- problem constants ----------
#define TT     2048
#define DM     1024
#define NH     16
#define HD     64
#define MROWS  4096   // B*T

// ---------- cast fp32 -> bf16, 4 elems/thread ----------
__global__ __launch_bounds__(256) void cast_f32_bf16(const float* __restrict__ src,
                                                     unsigned short* __restrict__ dst, int n4) {
    int i = blockIdx.x * 256 + threadIdx.x;
    if (i >= n4) return;
    float4 v = reinterpret_cast<const float4*>(src)[i];
    ushort4 o;
    o.x = f2bf(v.x); o.y = f2bf(v.y); o.z = f2bf(v.z); o.w = f2bf(v.w);
    reinterpret_cast<ushort4*>(dst)[i] = o;
}

// ==================== QKV GEMM: 256x256 tile, BK=64, 8 waves, counted-vmcnt dbuf ====
// out[m][n] = sum_k A[m][k] * W[n][k], M=4096, N=3072, K=1024. Epilogue scatters
// Q (x0.125), K, V (transposed) as bf16.
// LDS 128KB: A dbuf 2x32KB @0, B dbuf 2x32KB @64KB. Tile rows stride 128B (8 chunks
// of 16B); T2 swizzle: chunk ^= (row&7), realized as pre-swizzled GLOBAL source for
// global_load_lds (linear LDS dest) + swizzled ds_read address (rule #21).
__global__ __launch_bounds__(512, 1) void gemm_qkv_8w(const unsigned short* __restrict__ A,
                                                      const unsigned short* __restrict__ W,
                                                      unsigned short* __restrict__ qp,
                                                      unsigned short* __restrict__ kp,
                                                      unsigned short* __restrict__ vp) {
    extern __shared__ char lds[];

    const int tid = threadIdx.x;
    const int l = tid & 63;
    const int w = tid >> 6;          // 0..7
    const int r = l & 15, g = l >> 4;
    const int rb = r & 7;
    const int wr = w >> 2, wc = w & 3;   // 2 x 4 wave grid; wave tile 128x64

    // T1 bijective XCD swizzle: 192 blocks = 8 XCD x 24
    const int bid = blockIdx.x;
    const int swz = (bid & 7) * 24 + (bid >> 3);
    const int m0 = (swz & 15) * 256;
    const int n0 = (swz >> 4) * 256;

    // ---- staging geometry ----
    // Linear LDS chunk c = q*512 + w*64 + l  (16B units). row = c>>3, chunkcol = c&7.
    // Global source chunkcol = (c&7) ^ (row&7) = (l&7) ^ (l>>3)  [w*8 = 0 mod 8].
    const int lrow = l >> 3;                 // 0..7
    const int gch  = (l & 7) ^ lrow;         // pre-swizzled global chunk col
    const unsigned short* aG = A + (size_t)(m0 + w * 8 + lrow) * 1024 + gch * 8;
    const unsigned short* bG = W + (size_t)(n0 + w * 8 + lrow) * 1024 + gch * 8;
    const int lOff = (w * 64 + l) * 16;      // byte offset within buffer (+ q*8192)

#define QKV_STAGE(t)                                                             \
    do {                                                                         \
        char* ab = lds + ((t) & 1) * 32768;                                      \
        char* bb = lds + 65536 + ((t) & 1) * 32768;                              \
        _Pragma("unroll")                                                        \
        for (int q_ = 0; q_ < 4; ++q_) {                                         \
            gld_lds16(aG + q_ * 65536 + (t) * 64, ab + q_ * 8192 + lOff);        \
            gld_lds16(bG + q_ * 65536 + (t) * 64, bb + q_ * 8192 + lOff);        \
        }                                                                        \
    } while (0)

#define SYNC_FENCE() __builtin_amdgcn_sched_barrier(0)

    f32x4 acc[8][4];
#pragma unroll
    for (int i = 0; i < 8; i++)
#pragma unroll
        for (int j = 0; j < 4; j++) acc[i][j] = (f32x4){0.f, 0.f, 0.f, 0.f};

    // prologue: stage tiles 0 and 1; wait for tile 0 (own 8 oldest) then barrier
    QKV_STAGE(0);
    QKV_STAGE(1);
    asm volatile("s_waitcnt vmcnt(8)" ::: "memory");
    __builtin_amdgcn_s_barrier();
    SYNC_FENCE();

    // A-frag row base (bytes): row = wr*128 + i*16 + r, stride 128B; chunk ^= rb
    const char* aRd = lds + (wr * 128 + r) * 128;
    const char* bRd = lds + 65536 + (wc * 64 + r) * 128;

    for (int t = 0; t < 16; ++t) {
        const int boff = (t & 1) * 32768;
#pragma unroll
        for (int kk = 0; kk < 2; ++kk) {
            const int ch = ((kk * 4 + g) ^ rb) * 16;
            bf16x8 af[8], bff[4];
#pragma unroll
            for (int i = 0; i < 8; ++i)
                af[i] = *reinterpret_cast<const bf16x8*>(aRd + boff + i * 2048 + ch);
#pragma unroll
            for (int j = 0; j < 4; ++j)
                bff[j] = *reinterpret_cast<const bf16x8*>(bRd + boff + j * 2048 + ch);
            __builtin_amdgcn_s_setprio(1);
#pragma unroll
            for (int i = 0; i < 8; ++i)
#pragma unroll
                for (int j = 0; j < 4; ++j) acc[i][j] = MFMA16(af[i], bff[j], acc[i][j]);
            __builtin_amdgcn_s_setprio(0);
        }
        // tile consumed: barrier, stage t+2 into freed buffer, counted wait for t+1
        SYNC_FENCE();
        __builtin_amdgcn_s_barrier();
        SYNC_FENCE();
        if (t + 2 < 16) {
            QKV_STAGE(t + 2);
            asm volatile("s_waitcnt vmcnt(8)" ::: "memory");
        } else {
            asm volatile("s_waitcnt vmcnt(0)" ::: "memory");
        }
        __builtin_amdgcn_s_barrier();
        SYNC_FENCE();
    }

    // epilogue: C/D col = lane&15 (-> n), row = (lane>>4)*4 + reg (-> m)
#pragma unroll
    for (int i = 0; i < 8; ++i) {
#pragma unroll
        for (int j = 0; j < 4; ++j) {
#pragma unroll
            for (int reg = 0; reg < 4; ++reg) {
                const int mg = m0 + wr * 128 + i * 16 + g * 4 + reg;
                const int ng = n0 + wc * 64 + j * 16 + r;
                const float v = acc[i][j][reg];
                const int sel = ng >> 10;         // 0=Q 1=K 2=V (uniform per block)
                const int c10 = ng & 1023;
                const int h = c10 >> 6, d = c10 & 63;
                const int bb_ = mg >> 11, tq = mg & 2047;
                const int bh = bb_ * NH + h;
                if (sel == 0)      qp[(bh * TT + tq) * HD + d] = f2bf(v * 0.125f);
                else if (sel == 1) kp[(bh * TT + tq) * HD + d] = f2bf(v);
                else               vp[(bh * HD + d) * TT + tq] = f2bf(v);  // transposed
            }
        }
    }
#undef QKV_STAGE
#undef SYNC_FENCE
}

// ---------- out-proj GEMM (m97 structure, validated): out[m][n] = sum A[m][k]W[n][k]
__global__ __launch_bounds__(256) void gemm_out(const unsigned short* __restrict__ A,
                                                const unsigned short* __restrict__ W,
                                                float* __restrict__ out, int N) {
    __shared__ unsigned short lA[128 * 32];
    __shared__ unsigned short lB[128 * 32];

    const int tid = threadIdx.x;
    const int l = tid & 63;
    const int w = tid >> 6;
    const int r = l & 15;
    const int g = l >> 4;
    const int wr = w >> 1, wc = w & 1;
    const int m0 = blockIdx.x * 128, n0 = blockIdx.y * 128;

    f32x4 acc[4][4];
#pragma unroll
    for (int i = 0; i < 4; i++)
#pragma unroll
        for (int j = 0; j < 4; j++) acc[i][j] = (f32x4){0.f, 0.f, 0.f, 0.f};

    const int c0 = tid, c1 = tid + 256;
    const int row0 = c0 >> 2, col0 = (c0 & 3) * 8;
    const int row1 = c1 >> 2, col1 = (c1 & 3) * 8;
    const unsigned short* a0 = A + (m0 + row0) * 1024 + col0;
    const unsigned short* a1 = A + (m0 + row1) * 1024 + col1;
    const unsigned short* b0 = W + (n0 + row0) * 1024 + col0;
    const unsigned short* b1 = W + (n0 + row1) * 1024 + col1;
    unsigned short* la0 = lA + c0 * 8;
    unsigned short* la1 = lA + c1 * 8;
    unsigned short* lb0 = lB + c0 * 8;
    unsigned short* lb1 = lB + c1 * 8;

    for (int k0 = 0; k0 < 1024; k0 += 32) {
        gld_lds16(a0 + k0, la0);
        gld_lds16(a1 + k0, la1);
        gld_lds16(b0 + k0, lb0);
        gld_lds16(b1 + k0, lb1);
        __syncthreads();

        bf16x8 af[4], bfr[4];
#pragma unroll
        for (int i = 0; i < 4; i++)
            af[i] = *reinterpret_cast<const bf16x8*>(lA + (wr * 64 + i * 16 + r) * 32 + g * 8);
#pragma unroll
        for (int j = 0; j < 4; j++)
            bfr[j] = *reinterpret_cast<const bf16x8*>(lB + (wc * 64 + j * 16 + r) * 32 + g * 8);
#pragma unroll
        for (int i = 0; i < 4; i++)
#pragma unroll
            for (int j = 0; j < 4; j++) acc[i][j] = MFMA16(af[i], bfr[j], acc[i][j]);
        __syncthreads();
    }

#pragma unroll
    for (int i = 0; i < 4; i++)
#pragma unroll
        for (int j = 0; j < 4; j++)
#pragma unroll
            for (int reg = 0; reg < 4; reg++) {
                const int mg = m0 + wr * 64 + i * 16 + g * 4 + reg;
                const int ng = n0 + wc * 64 + j * 16 + r;
                out[mg * N + ng] = acc[i][j][reg];
            }
}

// ---------- flash attention, causal, swapped-QK^T structure (validated R2) ----------
__global__ __launch_bounds__(256) void attn_kernel(const unsigned short* __restrict__ q,
                                                   const unsigned short* __restrict__ k,
                                                   const unsigned short* __restrict__ v,
                                                   unsigned short* __restrict__ o) {
    __shared__ unsigned short lK[64 * 64];
    __shared__ unsigned short lV[64 * 64];

    const int tid = threadIdx.x;
    const int l   = tid & 63;
    const int w   = tid >> 6;
    const int c   = l & 31;
    const int hi  = l >> 5;

    const int id   = blockIdx.x;
    const int half = id >> 8;
    const int sub  = id & 255;
    const int bh   = sub >> 3;
    const int j8   = sub & 7;
    const int qt   = half ? (15 - j8) : j8;
    const int q0w  = qt * 128 + w * 32;
    const int nkt  = 2 * qt + 2;

    const unsigned short* qbase = q + (size_t)bh * TT * HD;
    const unsigned short* kbase = k + (size_t)bh * TT * HD;
    const unsigned short* vbase = v + (size_t)bh * HD * TT;

    bf16x8 qf[4];
#pragma unroll
    for (int ks = 0; ks < 4; ++ks)
        qf[ks] = *reinterpret_cast<const bf16x8*>(qbase + (q0w + c) * HD + ks * 16 + hi * 8);

    f32x16 Oacc[2];
#pragma unroll
    for (int jd = 0; jd < 2; ++jd)
#pragma unroll
        for (int e = 0; e < 16; ++e) Oacc[jd][e] = 0.f;
    float m_r = -1e30f, l_r = 0.f;

    const int cA = tid, cB = tid + 256;
    const int rA = cA >> 3, colA = (cA & 7) * 8;
    const int rB = cB >> 3, colB = (cB & 7) * 8;
    const int dstA = rA * 128 + ((colA * 2) ^ ((rA & 7) << 4));
    const int dstB = rB * 128 + ((colB * 2) ^ ((rB & 7) << 4));

    uint4 ka, kb, va, vb;
    ka = *reinterpret_cast<const uint4*>(kbase + rA * HD + colA);
    kb = *reinterpret_cast<const uint4*>(kbase + rB * HD + colB);
    va = *reinterpret_cast<const uint4*>(vbase + rA * TT + colA);
    vb = *reinterpret_cast<const uint4*>(vbase + rB * TT + colB);

    for (int kt = 0; kt < nkt; ++kt) {
        const int k0 = kt * 64;
        __syncthreads();
        *reinterpret_cast<uint4*>((char*)lK + dstA) = ka;
        *reinterpret_cast<uint4*>((char*)lK + dstB) = kb;
        *reinterpret_cast<uint4*>((char*)lV + dstA) = va;
        *reinterpret_cast<uint4*>((char*)lV + dstB) = vb;
        __syncthreads();
        if (kt + 1 < nkt) {
            const int kn = k0 + 64;
            ka = *reinterpret_cast<const uint4*>(kbase + (kn + rA) * HD + colA);
            kb = *reinterpret_cast<const uint4*>(kbase + (kn + rB) * HD + colB);
            va = *reinterpret_cast<const uint4*>(vbase + rA * TT + kn + colA);
            vb = *reinterpret_cast<const uint4*>(vbase + rB * TT + kn + colB);
        }
        if (k0 > q0w + 31) continue;

        f32x16 s[2];
#pragma unroll
        for (int j = 0; j < 2; ++j) {
#pragma unroll
            for (int e = 0; e < 16; ++e) s[j][e] = 0.f;
#pragma unroll
            for (int ks = 0; ks < 4; ++ks) {
                const int row = j * 32 + c;
                bf16x8 kf = *reinterpret_cast<const bf16x8*>(
                    (char*)lK + row * 128 + (((ks * 16 + hi * 8) * 2) ^ ((row & 7) << 4)));
                s[j] = MFMA32(kf, qf[ks], s[j]);
            }
        }

        if (k0 + 63 > q0w) {
            const int qg = q0w + c;
#pragma unroll
            for (int j = 0; j < 2; ++j)
#pragma unroll
                for (int e = 0; e < 16; ++e) {
                    const int kv = k0 + j * 32 + (e & 3) + 8 * (e >> 2) + 4 * hi;
                    if (kv > qg) s[j][e] = -1e30f;
                }
        }

        float mx = s[0][0];
#pragma unroll
        for (int e = 1; e < 16; ++e) mx = fmaxf(mx, s[0][e]);
#pragma unroll
        for (int e = 0; e < 16; ++e) mx = fmaxf(mx, s[1][e]);
        mx = fmaxf(mx, __shfl_xor(mx, 32));
        const float mnew = fmaxf(m_r, mx);
        const float corr = __expf(m_r - mnew);
        float sum = 0.f;
#pragma unroll
        for (int j = 0; j < 2; ++j)
#pragma unroll
            for (int e = 0; e < 16; ++e) {
                const float p = __expf(s[j][e] - mnew);
                s[j][e] = p;
                sum += p;
            }
        sum += __shfl_xor(sum, 32);
        l_r = l_r * corr + sum;
        m_r = mnew;
#pragma unroll
        for (int jd = 0; jd < 2; ++jd)
#pragma unroll
            for (int e = 0; e < 16; ++e) Oacc[jd][e] *= corr;

        bf16x8 pa[4];
#pragma unroll
        for (int ks = 0; ks < 4; ++ks) {
            const int j = ks >> 1;
            const int base = (ks & 1) * 8;
            const unsigned int pA0 = pk2(s[j][base + 0], s[j][base + 1]);
            const unsigned int pA1 = pk2(s[j][base + 2], s[j][base + 3]);
            const unsigned int pB0 = pk2(s[j][base + 4], s[j][base + 5]);
            const unsigned int pB1 = pk2(s[j][base + 6], s[j][base + 7]);
            const unsigned int m0_ = hi ? pB0 : pA0;
            const unsigned int m1_ = hi ? pB1 : pA1;
            const unsigned int o0 = hi ? pA0 : pB0;
            const unsigned int o1 = hi ? pA1 : pB1;
            const unsigned int r0 = __shfl_xor(o0, 32);
            const unsigned int r1 = __shfl_xor(o1, 32);
            uint4 u;
            u.x = hi ? r0 : m0_;
            u.y = hi ? r1 : m1_;
            u.z = hi ? m0_ : r0;
            u.w = hi ? m1_ : r1;
            pa[ks] = __builtin_bit_cast(bf16x8, u);
        }

#pragma unroll
        for (int jd = 0; jd < 2; ++jd) {
#pragma unroll
            for (int ks = 0; ks < 4; ++ks) {
                const int row = jd * 32 + c;
                bf16x8 vf = *reinterpret_cast<const bf16x8*>(
                    (char*)lV + row * 128 + (((ks * 16 + hi * 8) * 2) ^ ((row & 7) << 4)));
                Oacc[jd] = MFMA32(vf, pa[ks], Oacc[jd]);
            }
        }
    }

    const int b_ = bh >> 4, h_ = bh & 15;
    const float inv = 1.f / l_r;
    const int qg = q0w + c;
    unsigned short* orow = o + ((size_t)b_ * TT + qg) * DM + h_ * HD;
#pragma unroll
    for (int jd = 0; jd < 2; ++jd)
#pragma unroll
        for (int ep = 0; ep < 8; ++ep) {
            const int e0 = ep * 2;
            const int d0 = jd * 32 + (e0 & 3) + 8 * (e0 >> 2) + 4 * hi;
            const unsigned int pkv = pk2(Oacc[jd][e0] * inv, Oacc[jd][e0 + 1] * inv);
            *reinterpret_cast<unsigned int*>(orow + d0) = pkv;
        }
}

// ---------- launch ----------
extern "C" void kernel_launch(void* const* d_in, const int* in_sizes, int n_in,
                              void* d_out, int out_size, void* d_ws, size_t ws_size,
                              hipStream_t stream) {
    const float* x  = (const float*)d_in[0];
    const float* Wq = (const float*)d_in[1];
    const float* Wk = (const float*)d_in[2];
    const float* Wv = (const float*)d_in[3];
    const float* Wo = (const float*)d_in[4];
    // d_in[5] = attn_mask (causal; implemented analytically)

    char* ws = (char*)d_ws;
    unsigned short* xb   = (unsigned short*)(ws);                    //  8 MB  [4096][1024]
    unsigned short* wqkv = (unsigned short*)(ws + (8u  << 20));      //  6 MB  [3072][1024]
    unsigned short* wo   = (unsigned short*)(ws + (14u << 20));      //  2 MB  [1024][1024]
    unsigned short* qb   = (unsigned short*)(ws + (16u << 20));      //  8 MB  [32][2048][64]
    unsigned short* kb   = (unsigned short*)(ws + (24u << 20));      //  8 MB  [32][2048][64]
    unsigned short* vb   = (unsigned short*)(ws + (32u << 20));      //  8 MB  [32][64][2048]
    unsigned short* ab   = (unsigned short*)(ws + (40u << 20));      //  8 MB  [4096][1024]
    float* outp = (float*)d_out;

    cast_f32_bf16<<<4096, 256, 0, stream>>>(x, xb, 1048576);
    cast_f32_bf16<<<1024, 256, 0, stream>>>(Wq, wqkv, 262144);
    cast_f32_bf16<<<1024, 256, 0, stream>>>(Wk, wqkv + (1u << 20), 262144);
    cast_f32_bf16<<<1024, 256, 0, stream>>>(Wv, wqkv + (2u << 20), 262144);
    cast_f32_bf16<<<1024, 256, 0, stream>>>(Wo, wo, 262144);

    gemm_qkv_8w<<<192, 512, 131072, stream>>>(xb, wqkv, qb, kb, vb);
    attn_kernel<<<512, 256, 0, stream>>>(qb, kb, vb, ab);
    gemm_out<<<dim3(32, 8), 256, 0, stream>>>(ab, wo, outp, 1024);
}

// Round 8
// 220.731 us; speedup vs baseline: 1.0708x; 1.0708x over previous
//
#include <hip/hip_runtime.h>
#include <hip/hip_bf16.h>
#include <stdint.h>

// ---------- types ----------
typedef __bf16 bf16_t;
typedef bf16_t bf16x8 __attribute__((ext_vector_type(8)));
typedef float  f32x4  __attribute__((ext_vector_type(4)));
typedef float  f32x16 __attribute__((ext_vector_type(16)));

#define MFMA16(a, b, c) __builtin_amdgcn_mfma_f32_16x16x32_bf16((a), (b), (c), 0, 0, 0)
#define MFMA32(a, b, c) __builtin_amdgcn_mfma_f32_32x32x16_bf16((a), (b), (c), 0, 0, 0)

static __device__ __forceinline__ unsigned short f2bf(float f) {
    __hip_bfloat16 h = __float2bfloat16(f);
    return __builtin_bit_cast(unsigned short, h);
}
static __device__ __forceinline__ unsigned int pk2(float a, float b) {
    return ((unsigned int)f2bf(b) << 16) | (unsigned int)f2bf(a);
}

static __device__ __forceinline__ void gld_lds16(const void* g, void* l) {
    __builtin_amdgcn_global_load_lds(
        (const __attribute__((address_space(1))) uint32_t*)g,
        (__attribute__((address_space(3))) uint32_t*)l, 16, 0, 0);
}

// ---------- problem constants ----------
#define TT     2048
#define DM     1024
#define NH     16
#define HD     64

// ---------- casts ----------
__global__ __launch_bounds__(256) void cast_x(const float* __restrict__ src,
                                              unsigned short* __restrict__ dst, int n4) {
    int i = blockIdx.x * 256 + threadIdx.x;
    if (i >= n4) return;
    float4 v = reinterpret_cast<const float4*>(src)[i];
    ushort4 o;
    o.x = f2bf(v.x); o.y = f2bf(v.y); o.z = f2bf(v.z); o.w = f2bf(v.w);
    reinterpret_cast<ushort4*>(dst)[i] = o;
}

// all four weights in one launch: y selects the matrix (Wq,Wk,Wv -> wqkv; Wo -> wo)
__global__ __launch_bounds__(256) void cast_w(const float* __restrict__ wq,
                                              const float* __restrict__ wk,
                                              const float* __restrict__ wv,
                                              const float* __restrict__ wo_in,
                                              unsigned short* __restrict__ wqkv,
                                              unsigned short* __restrict__ wo_out) {
    const int y = blockIdx.y;
    const float* src = (y == 0) ? wq : (y == 1) ? wk : (y == 2) ? wv : wo_in;
    unsigned short* dst = (y < 3) ? (wqkv + (size_t)y * (1u << 20)) : wo_out;
    int i = blockIdx.x * 256 + threadIdx.x;   // 262144 float4 per matrix
    float4 v = reinterpret_cast<const float4*>(src)[i];
    ushort4 o;
    o.x = f2bf(v.x); o.y = f2bf(v.y); o.z = f2bf(v.z); o.w = f2bf(v.w);
    reinterpret_cast<ushort4*>(dst)[i] = o;
}

// ==================== 2-phase GEMM template (T3-minimum recipe, m248/m230) ============
// out[m][n] = sum_k A[m][k]*W[n][k], K=1024, BK=64, double-buffered LDS.
// Per tile: STAGE(next) FIRST, then ds_read+MFMA of current, then ONE __syncthreads()
// (emits s_waitcnt vmcnt(0) lgkmcnt(0); s_barrier == the recipe's vmcnt(0)+barrier).
// T2 swizzle: chunk ^= row&7 via pre-swizzled GLOBAL source (linear LDS dest, rule #21)
// + XOR on the ds_read address. T1 bijective XCD swizzle. T5 setprio around MFMA.
// MODE 0: QKV scatter epilogue (Q x0.125, K, V transposed, bf16). MODE 1: fp32 out.
template <int BM, int BN, int WM, int WN, int MODE>
__global__ __launch_bounds__(WM * WN * 64, 1)
void gemm2ph(const unsigned short* __restrict__ A, const unsigned short* __restrict__ W,
             float* __restrict__ out, int Nn,
             unsigned short* __restrict__ qp, unsigned short* __restrict__ kp,
             unsigned short* __restrict__ vp, int gridM) {
    constexpr int THREADS = WM * WN * 64;
    constexpr int MF = BM / WM / 16;
    constexpr int NF = BN / WN / 16;
    constexpr int ABYTES = BM * 128;            // 64 cols x 2B = 128 B/row
    constexpr int BUFB = ABYTES + BN * 128;     // one double-buffer slot (A then B)
    extern __shared__ char lds[];

    const int tid = threadIdx.x;
    const int l = tid & 63, w = tid >> 6;
    const int r = l & 15, g = l >> 4, rb = r & 7;
    const int wm = w / WN, wn = w % WN;

    // T1 bijective XCD swizzle (grid % 8 == 0 for both configs)
    const int bid = blockIdx.x;
    const int cpx = gridDim.x >> 3;
    const int swz = (bid & 7) * cpx + (bid >> 3);
    const int m0 = (swz % gridM) * BM;
    const int n0 = (swz / gridM) * BN;

    // staging geometry: chunk c = q_*THREADS + w*64 + l (16B units); row = c>>3,
    // lds col = c&7; global col pre-swizzled = (c&7) ^ (row&7) = (l&7)^(l>>3).
    const int lrow = l >> 3;
    const int gch = (l & 7) ^ lrow;
    const unsigned short* aG = A + (size_t)(m0 + w * 8 + lrow) * 1024 + gch * 8;
    const unsigned short* bG = W + (size_t)(n0 + w * 8 + lrow) * 1024 + gch * 8;
    const int lOff = (w * 64 + l) * 16;

#define STAGE(buf, t)                                                              \
    do {                                                                           \
        char* ab_ = lds + (buf) * BUFB;                                            \
        char* bb_ = ab_ + ABYTES;                                                  \
        _Pragma("unroll")                                                          \
        for (int q_ = 0; q_ < BM * 8 / THREADS; ++q_)                              \
            gld_lds16(aG + (size_t)q_ * (THREADS / 8) * 1024 + (t) * 64,           \
                      ab_ + q_ * THREADS * 16 + lOff);                             \
        _Pragma("unroll")                                                          \
        for (int q_ = 0; q_ < BN * 8 / THREADS; ++q_)                              \
            gld_lds16(bG + (size_t)q_ * (THREADS / 8) * 1024 + (t) * 64,           \
                      bb_ + q_ * THREADS * 16 + lOff);                             \
    } while (0)

    f32x4 acc[MF][NF];
#pragma unroll
    for (int i = 0; i < MF; i++)
#pragma unroll
        for (int j = 0; j < NF; j++) acc[i][j] = (f32x4){0.f, 0.f, 0.f, 0.f};

    STAGE(0, 0);
    __syncthreads();

    int cur = 0;
    for (int t = 0; t < 16; ++t) {
        if (t + 1 < 16) STAGE(cur ^ 1, t + 1);      // issue next-tile loads FIRST
        const char* aRd = lds + cur * BUFB + (wm * (BM / WM) + r) * 128;
        const char* bRd = lds + cur * BUFB + ABYTES + (wn * (BN / WN) + r) * 128;
#pragma unroll
        for (int kk = 0; kk < 2; ++kk) {
            const int ch = ((kk * 4 + g) ^ rb) * 16;
            bf16x8 af[MF], bfr[NF];
#pragma unroll
            for (int i = 0; i < MF; ++i)
                af[i] = *reinterpret_cast<const bf16x8*>(aRd + i * 2048 + ch);
#pragma unroll
            for (int j = 0; j < NF; ++j)
                bfr[j] = *reinterpret_cast<const bf16x8*>(bRd + j * 2048 + ch);
            __builtin_amdgcn_s_setprio(1);
#pragma unroll
            for (int i = 0; i < MF; ++i)
#pragma unroll
                for (int j = 0; j < NF; ++j) acc[i][j] = MFMA16(af[i], bfr[j], acc[i][j]);
            __builtin_amdgcn_s_setprio(0);
        }
        __syncthreads();   // vmcnt(0)+lgkmcnt(0)+barrier: next tile landed, cur free
        cur ^= 1;
    }
#undef STAGE

    // epilogue: C/D col = lane&15 (-> n), row = (lane>>4)*4 + reg (-> m)
#pragma unroll
    for (int i = 0; i < MF; ++i) {
#pragma unroll
        for (int j = 0; j < NF; ++j) {
#pragma unroll
            for (int reg = 0; reg < 4; ++reg) {
                const int mg = m0 + wm * (BM / WM) + i * 16 + g * 4 + reg;
                const int ng = n0 + wn * (BN / WN) + j * 16 + r;
                const float v = acc[i][j][reg];
                if constexpr (MODE == 1) {
                    out[(size_t)mg * Nn + ng] = v;
                } else {
                    const int sel = ng >> 10;       // 0=Q 1=K 2=V
                    const int c10 = ng & 1023;
                    const int h = c10 >> 6, d = c10 & 63;
                    const int bb_ = mg >> 11, tq = mg & 2047;
                    const int bh = bb_ * NH + h;
                    if (sel == 0)      qp[(bh * TT + tq) * HD + d] = f2bf(v * 0.125f);
                    else if (sel == 1) kp[(bh * TT + tq) * HD + d] = f2bf(v);
                    else               vp[(bh * HD + d) * TT + tq] = f2bf(v);  // transposed
                }
            }
        }
    }
}

// ---------- flash attention, causal, swapped-QK^T (validated R2/R3) ----------
__global__ __launch_bounds__(256) void attn_kernel(const unsigned short* __restrict__ q,
                                                   const unsigned short* __restrict__ k,
                                                   const unsigned short* __restrict__ v,
                                                   unsigned short* __restrict__ o) {
    __shared__ unsigned short lK[64 * 64];
    __shared__ unsigned short lV[64 * 64];

    const int tid = threadIdx.x;
    const int l   = tid & 63;
    const int w   = tid >> 6;
    const int c   = l & 31;
    const int hi  = l >> 5;

    const int id   = blockIdx.x;
    const int half = id >> 8;
    const int sub  = id & 255;
    const int bh   = sub >> 3;
    const int j8   = sub & 7;
    const int qt   = half ? (15 - j8) : j8;
    const int q0w  = qt * 128 + w * 32;
    const int nkt  = 2 * qt + 2;

    const unsigned short* qbase = q + (size_t)bh * TT * HD;
    const unsigned short* kbase = k + (size_t)bh * TT * HD;
    const unsigned short* vbase = v + (size_t)bh * HD * TT;

    bf16x8 qf[4];
#pragma unroll
    for (int ks = 0; ks < 4; ++ks)
        qf[ks] = *reinterpret_cast<const bf16x8*>(qbase + (q0w + c) * HD + ks * 16 + hi * 8);

    f32x16 Oacc[2];
#pragma unroll
    for (int jd = 0; jd < 2; ++jd)
#pragma unroll
        for (int e = 0; e < 16; ++e) Oacc[jd][e] = 0.f;
    float m_r = -1e30f, l_r = 0.f;

    const int cA = tid, cB = tid + 256;
    const int rA = cA >> 3, colA = (cA & 7) * 8;
    const int rB = cB >> 3, colB = (cB & 7) * 8;
    const int dstA = rA * 128 + ((colA * 2) ^ ((rA & 7) << 4));
    const int dstB = rB * 128 + ((colB * 2) ^ ((rB & 7) << 4));

    uint4 ka, kb, va, vb;
    ka = *reinterpret_cast<const uint4*>(kbase + rA * HD + colA);
    kb = *reinterpret_cast<const uint4*>(kbase + rB * HD + colB);
    va = *reinterpret_cast<const uint4*>(vbase + rA * TT + colA);
    vb = *reinterpret_cast<const uint4*>(vbase + rB * TT + colB);

    for (int kt = 0; kt < nkt; ++kt) {
        const int k0 = kt * 64;
        __syncthreads();
        *reinterpret_cast<uint4*>((char*)lK + dstA) = ka;
        *reinterpret_cast<uint4*>((char*)lK + dstB) = kb;
        *reinterpret_cast<uint4*>((char*)lV + dstA) = va;
        *reinterpret_cast<uint4*>((char*)lV + dstB) = vb;
        __syncthreads();
        if (kt + 1 < nkt) {
            const int kn = k0 + 64;
            ka = *reinterpret_cast<const uint4*>(kbase + (kn + rA) * HD + colA);
            kb = *reinterpret_cast<const uint4*>(kbase + (kn + rB) * HD + colB);
            va = *reinterpret_cast<const uint4*>(vbase + rA * TT + kn + colA);
            vb = *reinterpret_cast<const uint4*>(vbase + rB * TT + kn + colB);
        }
        if (k0 > q0w + 31) continue;

        f32x16 s[2];
#pragma unroll
        for (int j = 0; j < 2; ++j) {
#pragma unroll
            for (int e = 0; e < 16; ++e) s[j][e] = 0.f;
#pragma unroll
            for (int ks = 0; ks < 4; ++ks) {
                const int row = j * 32 + c;
                bf16x8 kf = *reinterpret_cast<const bf16x8*>(
                    (char*)lK + row * 128 + (((ks * 16 + hi * 8) * 2) ^ ((row & 7) << 4)));
                s[j] = MFMA32(kf, qf[ks], s[j]);
            }
        }

        if (k0 + 63 > q0w) {
            const int qg = q0w + c;
#pragma unroll
            for (int j = 0; j < 2; ++j)
#pragma unroll
                for (int e = 0; e < 16; ++e) {
                    const int kv = k0 + j * 32 + (e & 3) + 8 * (e >> 2) + 4 * hi;
                    if (kv > qg) s[j][e] = -1e30f;
                }
        }

        float mx = s[0][0];
#pragma unroll
        for (int e = 1; e < 16; ++e) mx = fmaxf(mx, s[0][e]);
#pragma unroll
        for (int e = 0; e < 16; ++e) mx = fmaxf(mx, s[1][e]);
        mx = fmaxf(mx, __shfl_xor(mx, 32));
        const float mnew = fmaxf(m_r, mx);
        const float corr = __expf(m_r - mnew);
        float sum = 0.f;
#pragma unroll
        for (int j = 0; j < 2; ++j)
#pragma unroll
            for (int e = 0; e < 16; ++e) {
                const float p = __expf(s[j][e] - mnew);
                s[j][e] = p;
                sum += p;
            }
        sum += __shfl_xor(sum, 32);
        l_r = l_r * corr + sum;
        m_r = mnew;
#pragma unroll
        for (int jd = 0; jd < 2; ++jd)
#pragma unroll
            for (int e = 0; e < 16; ++e) Oacc[jd][e] *= corr;

        bf16x8 pa[4];
#pragma unroll
        for (int ks = 0; ks < 4; ++ks) {
            const int j = ks >> 1;
            const int base = (ks & 1) * 8;
            const unsigned int pA0 = pk2(s[j][base + 0], s[j][base + 1]);
            const unsigned int pA1 = pk2(s[j][base + 2], s[j][base + 3]);
            const unsigned int pB0 = pk2(s[j][base + 4], s[j][base + 5]);
            const unsigned int pB1 = pk2(s[j][base + 6], s[j][base + 7]);
            const unsigned int m0_ = hi ? pB0 : pA0;
            const unsigned int m1_ = hi ? pB1 : pA1;
            const unsigned int o0 = hi ? pA0 : pB0;
            const unsigned int o1 = hi ? pA1 : pB1;
            const unsigned int r0 = __shfl_xor(o0, 32);
            const unsigned int r1 = __shfl_xor(o1, 32);
            uint4 u;
            u.x = hi ? r0 : m0_;
            u.y = hi ? r1 : m1_;
            u.z = hi ? m0_ : r0;
            u.w = hi ? m1_ : r1;
            pa[ks] = __builtin_bit_cast(bf16x8, u);
        }

#pragma unroll
        for (int jd = 0; jd < 2; ++jd) {
#pragma unroll
            for (int ks = 0; ks < 4; ++ks) {
                const int row = jd * 32 + c;
                bf16x8 vf = *reinterpret_cast<const bf16x8*>(
                    (char*)lV + row * 128 + (((ks * 16 + hi * 8) * 2) ^ ((row & 7) << 4)));
                Oacc[jd] = MFMA32(vf, pa[ks], Oacc[jd]);
            }
        }
    }

    const int b_ = bh >> 4, h_ = bh & 15;
    const float inv = 1.f / l_r;
    const int qg = q0w + c;
    unsigned short* orow = o + ((size_t)b_ * TT + qg) * DM + h_ * HD;
#pragma unroll
    for (int jd = 0; jd < 2; ++jd)
#pragma unroll
        for (int ep = 0; ep < 8; ++ep) {
            const int e0 = ep * 2;
            const int d0 = jd * 32 + (e0 & 3) + 8 * (e0 >> 2) + 4 * hi;
            const unsigned int pkv = pk2(Oacc[jd][e0] * inv, Oacc[jd][e0 + 1] * inv);
            *reinterpret_cast<unsigned int*>(orow + d0) = pkv;
        }
}

// ---------- launch ----------
extern "C" void kernel_launch(void* const* d_in, const int* in_sizes, int n_in,
                              void* d_out, int out_size, void* d_ws, size_t ws_size,
                              hipStream_t stream) {
    const float* x  = (const float*)d_in[0];
    const float* Wq = (const float*)d_in[1];
    const float* Wk = (const float*)d_in[2];
    const float* Wv = (const float*)d_in[3];
    const float* Wo = (const float*)d_in[4];
    // d_in[5] = attn_mask (causal; implemented analytically)

    char* ws = (char*)d_ws;
    unsigned short* xb   = (unsigned short*)(ws);                    //  8 MB  [4096][1024]
    unsigned short* wqkv = (unsigned short*)(ws + (8u  << 20));      //  6 MB  [3072][1024]
    unsigned short* wo   = (unsigned short*)(ws + (14u << 20));      //  2 MB  [1024][1024]
    unsigned short* qb   = (unsigned short*)(ws + (16u << 20));      //  8 MB  [32][2048][64]
    unsigned short* kb   = (unsigned short*)(ws + (24u << 20));      //  8 MB  [32][2048][64]
    unsigned short* vb   = (unsigned short*)(ws + (32u << 20));      //  8 MB  [32][64][2048]
    unsigned short* ab   = (unsigned short*)(ws + (40u << 20));      //  8 MB  [4096][1024]
    float* outp = (float*)d_out;

    cast_x<<<4096, 256, 0, stream>>>(x, xb, 1048576);
    cast_w<<<dim3(1024, 4), 256, 0, stream>>>(Wq, Wk, Wv, Wo, wqkv, wo);

    gemm2ph<256, 256, 2, 4, 0><<<192, 512, 131072, stream>>>(
        xb, wqkv, nullptr, 3072, qb, kb, vb, 16);
    attn_kernel<<<512, 256, 0, stream>>>(qb, kb, vb, ab);
    gemm2ph<128, 128, 2, 2, 1><<<256, 256, 65536, stream>>>(
        ab, wo, outp, 1024, nullptr, nullptr, nullptr, 32);
}

// Round 10
// 219.908 us; speedup vs baseline: 1.0748x; 1.0037x over previous
//
#include <hip/hip_runtime.h>
#include <hip/hip_bf16.h>
#include <stdint.h>

// ---------- types ----------
typedef __bf16 bf16_t;
typedef bf16_t bf16x8 __attribute__((ext_vector_type(8)));
typedef float  f32x4  __attribute__((ext_vector_type(4)));
typedef float  f32x16 __attribute__((ext_vector_type(16)));

#define MFMA16(a, b, c) __builtin_amdgcn_mfma_f32_16x16x32_bf16((a), (b), (c), 0, 0, 0)
#define MFMA32(a, b, c) __builtin_amdgcn_mfma_f32_32x32x16_bf16((a), (b), (c), 0, 0, 0)

static __device__ __forceinline__ unsigned short f2bf(float f) {
    __hip_bfloat16 h = __float2bfloat16(f);
    return __builtin_bit_cast(unsigned short, h);
}
static __device__ __forceinline__ unsigned int pk2(float a, float b) {
    return ((unsigned int)f2bf(b) << 16) | (unsigned int)f2bf(a);
}

static __device__ __forceinline__ void gld_lds16(const void* g, void* l) {
    __builtin_amdgcn_global_load_lds(
        (const __attribute__((address_space(1))) uint32_t*)g,
        (__attribute__((address_space(3))) uint32_t*)l, 16, 0, 0);
}

// ---------- problem constants ----------
#define TT     2048
#define DM     1024
#define NH     16
#define HD     64

// ---------- casts ----------
__global__ __launch_bounds__(256) void cast_x(const float* __restrict__ src,
                                              unsigned short* __restrict__ dst, int n4) {
    int i = blockIdx.x * 256 + threadIdx.x;
    if (i >= n4) return;
    float4 v = reinterpret_cast<const float4*>(src)[i];
    ushort4 o;
    o.x = f2bf(v.x); o.y = f2bf(v.y); o.z = f2bf(v.z); o.w = f2bf(v.w);
    reinterpret_cast<ushort4*>(dst)[i] = o;
}

__global__ __launch_bounds__(256) void cast_w(const float* __restrict__ wq,
                                              const float* __restrict__ wk,
                                              const float* __restrict__ wv,
                                              const float* __restrict__ wo_in,
                                              unsigned short* __restrict__ wqkv,
                                              unsigned short* __restrict__ wo_out) {
    const int y = blockIdx.y;
    const float* src = (y == 0) ? wq : (y == 1) ? wk : (y == 2) ? wv : wo_in;
    unsigned short* dst = (y < 3) ? (wqkv + (size_t)y * (1u << 20)) : wo_out;
    int i = blockIdx.x * 256 + threadIdx.x;
    float4 v = reinterpret_cast<const float4*>(src)[i];
    ushort4 o;
    o.x = f2bf(v.x); o.y = f2bf(v.y); o.z = f2bf(v.z); o.w = f2bf(v.w);
    reinterpret_cast<ushort4*>(dst)[i] = o;
}

// ==================== 4-deep pipelined GEMM: BK=32, 4 LDS buffers, 1 barrier/tile ====
// out[m][n] = sum_k A[m][k]*W[n][k], K=1024 (32 tiles of BK=32), 512 threads.
// Steady state: 3 tiles of loads in flight per wave (vmcnt(2*IPT), never drained to 0
// in the main loop). Per tile t: vmcnt -> barrier -> ds_read buf(t&3) -> STAGE(t+3)
// into buf((t-1)&3) -> MFMA. Sync proof: each wave's tile-t loads retire (own vmcnt)
// before barrier(t); reads of buf((t-1)&3) retire (lgkmcnt forced by MFMA dep) before
// the owning wave reaches barrier(t); STAGE(t+3) is issued only after barrier(t).
// T2: chunk ^= row&3 via pre-swizzled global source (linear LDS dest) + XOR on read.
// MODE 0: QKV scatter epilogue (Q x0.125, K, V transposed). MODE 1: fp32 out.
template <int BM, int BN, int WM, int WN, int MODE>
__global__ __launch_bounds__(512, 1)
void gemm4d(const unsigned short* __restrict__ A, const unsigned short* __restrict__ W,
            float* __restrict__ out, int Nn,
            unsigned short* __restrict__ qp, unsigned short* __restrict__ kp,
            unsigned short* __restrict__ vp, int gridM) {
    constexpr int THREADS = WM * WN * 64;
    static_assert(THREADS == 512, "template assumes 512 threads");
    constexpr int MF = BM / WM / 16;
    constexpr int NF = BN / WN / 16;
    constexpr int ABYTES = BM * 64;          // BK=32 cols * 2B = 64 B/row
    constexpr int BUFB = ABYTES + BN * 64;   // one of 4 buffers (A then B)
    constexpr int APT = BM / 128;            // A-loads per thread per tile
    constexpr int BPT = BN / 128;
    constexpr int IPT = APT + BPT;
    extern __shared__ char lds[];

    const int tid = threadIdx.x;
    const int l = tid & 63, w = tid >> 6;
    const int r = l & 15, g = l >> 4;
    const int wm = w / WN, wn = w % WN;

    // T1 bijective XCD swizzle (grid % 8 == 0)
    const int bid = blockIdx.x;
    const int cpx = gridDim.x >> 3;
    const int swz = (bid & 7) * cpx + (bid >> 3);
    const int m0 = (swz % gridM) * BM;
    const int n0 = (swz / gridM) * BN;

    // staging: chunk c = q*512 + tid (16B units); row = c>>2, ldscol = c&3,
    // global col pre-swizzled = (c&3)^(row&3). (512/4=128 rows per q, 128%4==0.)
    const int srow = tid >> 2;
    const int gcol = (tid & 3) ^ (srow & 3);
    const unsigned short* aG = A + (size_t)(m0 + srow) * 1024 + gcol * 8;
    const unsigned short* bG = W + (size_t)(n0 + srow) * 1024 + gcol * 8;

#define STAGE4(buf, t)                                                         \
    do {                                                                       \
        char* ab_ = lds + (buf) * BUFB;                                        \
        char* bb_ = ab_ + ABYTES;                                              \
        _Pragma("unroll")                                                      \
        for (int q_ = 0; q_ < APT; ++q_)                                       \
            gld_lds16(aG + (size_t)q_ * 128 * 1024 + (t) * 32,                 \
                      ab_ + q_ * 8192 + tid * 16);                             \
        _Pragma("unroll")                                                      \
        for (int q_ = 0; q_ < BPT; ++q_)                                       \
            gld_lds16(bG + (size_t)q_ * 128 * 1024 + (t) * 32,                 \
                      bb_ + q_ * 8192 + tid * 16);                             \
    } while (0)

    f32x4 acc[MF][NF];
#pragma unroll
    for (int i = 0; i < MF; i++)
#pragma unroll
        for (int j = 0; j < NF; j++) acc[i][j] = (f32x4){0.f, 0.f, 0.f, 0.f};

    // prologue: 3 tiles in flight
    STAGE4(0, 0);
    STAGE4(1, 1);
    STAGE4(2, 2);

    const int rdsw = ((g ^ (r & 3)) << 4);   // read-side XOR swizzle (row&3 == r&3)

    for (int t = 0; t < 32; ++t) {
        // retire own tile-t loads; keep up to 2 future tiles in flight
        if constexpr (IPT == 4) {
            if (t <= 29)      asm volatile("s_waitcnt vmcnt(8)" ::: "memory");
            else if (t == 30) asm volatile("s_waitcnt vmcnt(4)" ::: "memory");
            else              asm volatile("s_waitcnt vmcnt(0)" ::: "memory");
        } else {
            if (t <= 29)      asm volatile("s_waitcnt vmcnt(4)" ::: "memory");
            else if (t == 30) asm volatile("s_waitcnt vmcnt(2)" ::: "memory");
            else              asm volatile("s_waitcnt vmcnt(0)" ::: "memory");
        }
        __builtin_amdgcn_sched_barrier(0);
        __builtin_amdgcn_s_barrier();
        __builtin_amdgcn_sched_barrier(0);

        const char* ab_ = lds + (t & 3) * BUFB;
        const char* bb_ = ab_ + ABYTES;
        bf16x8 af[MF], bfr[NF];
#pragma unroll
        for (int i = 0; i < MF; ++i)
            af[i] = *reinterpret_cast<const bf16x8*>(
                ab_ + (wm * (BM / WM) + i * 16 + r) * 64 + rdsw);
#pragma unroll
        for (int j = 0; j < NF; ++j)
            bfr[j] = *reinterpret_cast<const bf16x8*>(
                bb_ + (wn * (BN / WN) + j * 16 + r) * 64 + rdsw);

        if (t < 29) STAGE4((t + 3) & 3, t + 3);   // after barrier: buf (t-1)&3 is free

        __builtin_amdgcn_s_setprio(1);
#pragma unroll
        for (int i = 0; i < MF; ++i)
#pragma unroll
            for (int j = 0; j < NF; ++j) acc[i][j] = MFMA16(af[i], bfr[j], acc[i][j]);
        __builtin_amdgcn_s_setprio(0);
    }
#undef STAGE4

    // epilogue: C/D col = lane&15 (-> n), row = (lane>>4)*4 + reg (-> m)
#pragma unroll
    for (int i = 0; i < MF; ++i) {
#pragma unroll
        for (int j = 0; j < NF; ++j) {
#pragma unroll
            for (int reg = 0; reg < 4; ++reg) {
                const int mg = m0 + wm * (BM / WM) + i * 16 + g * 4 + reg;
                const int ng = n0 + wn * (BN / WN) + j * 16 + r;
                const float v = acc[i][j][reg];
                if constexpr (MODE == 1) {
                    out[(size_t)mg * Nn + ng] = v;
                } else {
                    const int sel = ng >> 10;       // 0=Q 1=K 2=V
                    const int c10 = ng & 1023;
                    const int h = c10 >> 6, d = c10 & 63;
                    const int bb2 = mg >> 11, tq = mg & 2047;
                    const int bh = bb2 * NH + h;
                    if (sel == 0)      qp[(bh * TT + tq) * HD + d] = f2bf(v * 0.125f);
                    else if (sel == 1) kp[(bh * TT + tq) * HD + d] = f2bf(v);
                    else               vp[(bh * HD + d) * TT + tq] = f2bf(v);  // transposed
                }
            }
        }
    }
}

// ---------- flash attention, causal, swapped-QK^T (validated R2-R8, unchanged) ----------
__global__ __launch_bounds__(256) void attn_kernel(const unsigned short* __restrict__ q,
                                                   const unsigned short* __restrict__ k,
                                                   const unsigned short* __restrict__ v,
                                                   unsigned short* __restrict__ o) {
    __shared__ unsigned short lK[64 * 64];
    __shared__ unsigned short lV[64 * 64];

    const int tid = threadIdx.x;
    const int l   = tid & 63;
    const int w   = tid >> 6;
    const int c   = l & 31;
    const int hi  = l >> 5;

    const int id   = blockIdx.x;
    const int half = id >> 8;
    const int sub  = id & 255;
    const int bh   = sub >> 3;
    const int j8   = sub & 7;
    const int qt   = half ? (15 - j8) : j8;
    const int q0w  = qt * 128 + w * 32;
    const int nkt  = 2 * qt + 2;

    const unsigned short* qbase = q + (size_t)bh * TT * HD;
    const unsigned short* kbase = k + (size_t)bh * TT * HD;
    const unsigned short* vbase = v + (size_t)bh * HD * TT;

    bf16x8 qf[4];
#pragma unroll
    for (int ks = 0; ks < 4; ++ks)
        qf[ks] = *reinterpret_cast<const bf16x8*>(qbase + (q0w + c) * HD + ks * 16 + hi * 8);

    f32x16 Oacc[2];
#pragma unroll
    for (int jd = 0; jd < 2; ++jd)
#pragma unroll
        for (int e = 0; e < 16; ++e) Oacc[jd][e] = 0.f;
    float m_r = -1e30f, l_r = 0.f;

    const int cA = tid, cB = tid + 256;
    const int rA = cA >> 3, colA = (cA & 7) * 8;
    const int rB = cB >> 3, colB = (cB & 7) * 8;
    const int dstA = rA * 128 + ((colA * 2) ^ ((rA & 7) << 4));
    const int dstB = rB * 128 + ((colB * 2) ^ ((rB & 7) << 4));

    uint4 ka, kb, va, vb;
    ka = *reinterpret_cast<const uint4*>(kbase + rA * HD + colA);
    kb = *reinterpret_cast<const uint4*>(kbase + rB * HD + colB);
    va = *reinterpret_cast<const uint4*>(vbase + rA * TT + colA);
    vb = *reinterpret_cast<const uint4*>(vbase + rB * TT + colB);

    for (int kt = 0; kt < nkt; ++kt) {
        const int k0 = kt * 64;
        __syncthreads();
        *reinterpret_cast<uint4*>((char*)lK + dstA) = ka;
        *reinterpret_cast<uint4*>((char*)lK + dstB) = kb;
        *reinterpret_cast<uint4*>((char*)lV + dstA) = va;
        *reinterpret_cast<uint4*>((char*)lV + dstB) = vb;
        __syncthreads();
        if (kt + 1 < nkt) {
            const int kn = k0 + 64;
            ka = *reinterpret_cast<const uint4*>(kbase + (kn + rA) * HD + colA);
            kb = *reinterpret_cast<const uint4*>(kbase + (kn + rB) * HD + colB);
            va = *reinterpret_cast<const uint4*>(vbase + rA * TT + kn + colA);
            vb = *reinterpret_cast<const uint4*>(vbase + rB * TT + kn + colB);
        }
        if (k0 > q0w + 31) continue;

        f32x16 s[2];
#pragma unroll
        for (int j = 0; j < 2; ++j) {
#pragma unroll
            for (int e = 0; e < 16; ++e) s[j][e] = 0.f;
#pragma unroll
            for (int ks = 0; ks < 4; ++ks) {
                const int row = j * 32 + c;
                bf16x8 kf = *reinterpret_cast<const bf16x8*>(
                    (char*)lK + row * 128 + (((ks * 16 + hi * 8) * 2) ^ ((row & 7) << 4)));
                s[j] = MFMA32(kf, qf[ks], s[j]);
            }
        }

        if (k0 + 63 > q0w) {
            const int qg = q0w + c;
#pragma unroll
            for (int j = 0; j < 2; ++j)
#pragma unroll
                for (int e = 0; e < 16; ++e) {
                    const int kv = k0 + j * 32 + (e & 3) + 8 * (e >> 2) + 4 * hi;
                    if (kv > qg) s[j][e] = -1e30f;
                }
        }

        float mx = s[0][0];
#pragma unroll
        for (int e = 1; e < 16; ++e) mx = fmaxf(mx, s[0][e]);
#pragma unroll
        for (int e = 0; e < 16; ++e) mx = fmaxf(mx, s[1][e]);
        mx = fmaxf(mx, __shfl_xor(mx, 32));
        const float mnew = fmaxf(m_r, mx);
        const float corr = __expf(m_r - mnew);
        float sum = 0.f;
#pragma unroll
        for (int j = 0; j < 2; ++j)
#pragma unroll
            for (int e = 0; e < 16; ++e) {
                const float p = __expf(s[j][e] - mnew);
                s[j][e] = p;
                sum += p;
            }
        sum += __shfl_xor(sum, 32);
        l_r = l_r * corr + sum;
        m_r = mnew;
#pragma unroll
        for (int jd = 0; jd < 2; ++jd)
#pragma unroll
            for (int e = 0; e < 16; ++e) Oacc[jd][e] *= corr;

        bf16x8 pa[4];
#pragma unroll
        for (int ks = 0; ks < 4; ++ks) {
            const int j = ks >> 1;
            const int base = (ks & 1) * 8;
            const unsigned int pA0 = pk2(s[j][base + 0], s[j][base + 1]);
            const unsigned int pA1 = pk2(s[j][base + 2], s[j][base + 3]);
            const unsigned int pB0 = pk2(s[j][base + 4], s[j][base + 5]);
            const unsigned int pB1 = pk2(s[j][base + 6], s[j][base + 7]);
            const unsigned int m0_ = hi ? pB0 : pA0;
            const unsigned int m1_ = hi ? pB1 : pA1;
            const unsigned int o0 = hi ? pA0 : pB0;
            const unsigned int o1 = hi ? pA1 : pB1;
            const unsigned int r0 = __shfl_xor(o0, 32);
            const unsigned int r1 = __shfl_xor(o1, 32);
            uint4 u;
            u.x = hi ? r0 : m0_;
            u.y = hi ? r1 : m1_;
            u.z = hi ? m0_ : r0;
            u.w = hi ? m1_ : r1;
            pa[ks] = __builtin_bit_cast(bf16x8, u);
        }

#pragma unroll
        for (int jd = 0; jd < 2; ++jd) {
#pragma unroll
            for (int ks = 0; ks < 4; ++ks) {
                const int row = jd * 32 + c;
                bf16x8 vf = *reinterpret_cast<const bf16x8*>(
                    (char*)lV + row * 128 + (((ks * 16 + hi * 8) * 2) ^ ((row & 7) << 4)));
                Oacc[jd] = MFMA32(vf, pa[ks], Oacc[jd]);
            }
        }
    }

    const int b_ = bh >> 4, h_ = bh & 15;
    const float inv = 1.f / l_r;
    const int qg = q0w + c;
    unsigned short* orow = o + ((size_t)b_ * TT + qg) * DM + h_ * HD;
#pragma unroll
    for (int jd = 0; jd < 2; ++jd)
#pragma unroll
        for (int ep = 0; ep < 8; ++ep) {
            const int e0 = ep * 2;
            const int d0 = jd * 32 + (e0 & 3) + 8 * (e0 >> 2) + 4 * hi;
            const unsigned int pkv = pk2(Oacc[jd][e0] * inv, Oacc[jd][e0 + 1] * inv);
            *reinterpret_cast<unsigned int*>(orow + d0) = pkv;
        }
}

// ---------- launch ----------
extern "C" void kernel_launch(void* const* d_in, const int* in_sizes, int n_in,
                              void* d_out, int out_size, void* d_ws, size_t ws_size,
                              hipStream_t stream) {
    const float* x  = (const float*)d_in[0];
    const float* Wq = (const float*)d_in[1];
    const float* Wk = (const float*)d_in[2];
    const float* Wv = (const float*)d_in[3];
    const float* Wo = (const float*)d_in[4];
    // d_in[5] = attn_mask (causal; implemented analytically)

    char* ws = (char*)d_ws;
    unsigned short* xb   = (unsigned short*)(ws);                    //  8 MB  [4096][1024]
    unsigned short* wqkv = (unsigned short*)(ws + (8u  << 20));      //  6 MB  [3072][1024]
    unsigned short* wo   = (unsigned short*)(ws + (14u << 20));      //  2 MB  [1024][1024]
    unsigned short* qb   = (unsigned short*)(ws + (16u << 20));      //  8 MB  [32][2048][64]
    unsigned short* kb   = (unsigned short*)(ws + (24u << 20));      //  8 MB  [32][2048][64]
    unsigned short* vb   = (unsigned short*)(ws + (32u << 20));      //  8 MB  [32][64][2048]
    unsigned short* ab   = (unsigned short*)(ws + (40u << 20));      //  8 MB  [4096][1024]
    float* outp = (float*)d_out;

    cast_x<<<4096, 256, 0, stream>>>(x, xb, 1048576);
    cast_w<<<dim3(1024, 4), 256, 0, stream>>>(Wq, Wk, Wv, Wo, wqkv, wo);

    gemm4d<256, 256, 2, 4, 0><<<192, 512, 131072, stream>>>(
        xb, wqkv, nullptr, 3072, qb, kb, vb, 16);
    attn_kernel<<<512, 256, 0, stream>>>(qb, kb, vb, ab);
    gemm4d<128, 128, 4, 2, 1><<<256, 512, 65536, stream>>>(
        ab, wo, outp, 1024, nullptr, nullptr, nullptr, 32);
}